// Round 1
// baseline (901.093 us; speedup 1.0000x reference)
//
#include <hip/hip_runtime.h>

#define NNODES 50000
#define NEDGES 1600000
#define INF 128
#define UNITS 64
#define OUTF 40
#define NLAYERS 6
#define SCAN_B 512
#define NCHUNK ((NNODES + SCAN_B - 1) / SCAN_B)  // 98

__global__ void k_zero(int* __restrict__ p, int n) {
  int i = blockIdx.x * 256 + threadIdx.x;
  if (i < n) p[i] = 0;
}

__global__ void k_hist(const int* __restrict__ dst, int* __restrict__ cnt) {
  int e = blockIdx.x * 256 + threadIdx.x;
  if (e < NEDGES) atomicAdd(&cnt[dst[e]], 1);
}

__global__ void k_scan1(const int* __restrict__ cnt, int* __restrict__ row_ptr,
                        int* __restrict__ partials) {
  __shared__ int sh[SCAN_B];
  int i = blockIdx.x * SCAN_B + threadIdx.x;
  int v = (i < NNODES) ? cnt[i] : 0;
  sh[threadIdx.x] = v;
  __syncthreads();
  for (int off = 1; off < SCAN_B; off <<= 1) {
    int t = (threadIdx.x >= off) ? sh[threadIdx.x - off] : 0;
    __syncthreads();
    sh[threadIdx.x] += t;
    __syncthreads();
  }
  if (i < NNODES) row_ptr[i + 1] = sh[threadIdx.x];
  if (threadIdx.x == SCAN_B - 1) partials[blockIdx.x] = sh[SCAN_B - 1];
}

__global__ void k_scan2(int* __restrict__ partials, int* __restrict__ row_ptr) {
  if (threadIdx.x == 0 && blockIdx.x == 0) {
    int run = 0;
    for (int i = 0; i < NCHUNK; ++i) { int t = partials[i]; partials[i] = run; run += t; }
    row_ptr[0] = 0;
  }
}

__global__ void k_scan3(int* __restrict__ row_ptr, const int* __restrict__ partials) {
  int i = blockIdx.x * SCAN_B + threadIdx.x;
  if (i < NNODES) row_ptr[i + 1] += partials[blockIdx.x];
}

__global__ void k_cursor(const int* __restrict__ row_ptr, int* __restrict__ cursor) {
  int i = blockIdx.x * 256 + threadIdx.x;
  if (i < NNODES) cursor[i] = row_ptr[i];
}

__global__ void k_place(const int* __restrict__ src, const int* __restrict__ dst,
                        int* __restrict__ cursor, int* __restrict__ srcs) {
  int e = blockIdx.x * 256 + threadIdx.x;
  if (e < NEDGES) {
    int p = atomicAdd(&cursor[dst[e]], 1);
    srcs[p] = src[e];
  }
}

// z = h @ wl ; s = h @ ws + (bl + bs + bias)
// block = 256 threads = 4 waves; each wave handles 4 consecutive nodes (16/block).
template <int IN>
__global__ void k_transform(const float* __restrict__ h, const float* __restrict__ wl,
                            const float* __restrict__ ws, const float* __restrict__ bl,
                            const float* __restrict__ bs, const float* __restrict__ bias,
                            float* __restrict__ z, float* __restrict__ s) {
  __shared__ float lds_h[16 * IN];
  const float* hbase = h + (size_t)blockIdx.x * 16 * IN;
  for (int idx = threadIdx.x; idx < 16 * IN; idx += 256) lds_h[idx] = hbase[idx];
  __syncthreads();
  int wave = threadIdx.x >> 6;
  int lane = threadIdx.x & 63;
  int nb = blockIdx.x * 16 + wave * 4;
  const float* hl = &lds_h[(wave * 4) * IN];
  float za0 = 0, za1 = 0, za2 = 0, za3 = 0;
  float sa0 = 0, sa1 = 0, sa2 = 0, sa3 = 0;
#pragma unroll 4
  for (int k = 0; k < IN; ++k) {
    float wlv = wl[k * 64 + lane];
    float wsv = ws[k * 64 + lane];
    float h0 = hl[k], h1 = hl[IN + k], h2 = hl[2 * IN + k], h3 = hl[3 * IN + k];
    za0 += h0 * wlv; sa0 += h0 * wsv;
    za1 += h1 * wlv; sa1 += h1 * wsv;
    za2 += h2 * wlv; sa2 += h2 * wsv;
    za3 += h3 * wlv; sa3 += h3 * wsv;
  }
  float c = bl[lane] + bs[lane] + bias[lane];
  z[(size_t)(nb + 0) * 64 + lane] = za0; s[(size_t)(nb + 0) * 64 + lane] = sa0 + c;
  z[(size_t)(nb + 1) * 64 + lane] = za1; s[(size_t)(nb + 1) * 64 + lane] = sa1 + c;
  z[(size_t)(nb + 2) * 64 + lane] = za2; s[(size_t)(nb + 2) * 64 + lane] = sa2 + c;
  z[(size_t)(nb + 3) * 64 + lane] = za3; s[(size_t)(nb + 3) * 64 + lane] = sa3 + c;
}

// agg = sum_{e in CSR(node)} z[src_e]; h_out = relu(agg + s); out (+)= h_out @ wlast_slice
// block = 256 = 4 waves, one node per wave.
__global__ void k_aggregate(const int* __restrict__ row_ptr, const int* __restrict__ srcs,
                            const float* __restrict__ z, const float* __restrict__ s,
                            const float* __restrict__ wlast, const float* __restrict__ blast,
                            float* __restrict__ h_out, float* __restrict__ out, int layer) {
  __shared__ float lds_h[4][64];
  int wave = threadIdx.x >> 6;
  int lane = threadIdx.x & 63;
  int node = blockIdx.x * 4 + wave;
  int start = row_ptr[node];
  int end = row_ptr[node + 1];
  float a0 = 0, a1 = 0, a2 = 0, a3 = 0;
  int e = start;
  for (; e + 4 <= end; e += 4) {
    int s0 = srcs[e], s1 = srcs[e + 1], s2 = srcs[e + 2], s3 = srcs[e + 3];
    a0 += z[(size_t)s0 * 64 + lane];
    a1 += z[(size_t)s1 * 64 + lane];
    a2 += z[(size_t)s2 * 64 + lane];
    a3 += z[(size_t)s3 * 64 + lane];
  }
  for (; e < end; ++e) a0 += z[(size_t)srcs[e] * 64 + lane];
  float hv = (a0 + a1) + (a2 + a3) + s[(size_t)node * 64 + lane];
  hv = fmaxf(hv, 0.f);
  h_out[(size_t)node * 64 + lane] = hv;
  lds_h[wave][lane] = hv;
  __syncthreads();
  if (lane < OUTF) {
    float o = 0.f;
#pragma unroll 8
    for (int d = 0; d < 64; ++d) o += lds_h[wave][d] * wlast[d * OUTF + lane];
    float prev = (layer == 0) ? blast[lane] : out[(size_t)node * OUTF + lane];
    out[(size_t)node * OUTF + lane] = prev + o;
  }
}

static inline size_t align16(size_t x) { return (x + 15) & ~(size_t)15; }

extern "C" void kernel_launch(void* const* d_in, const int* in_sizes, int n_in,
                              void* d_out, int out_size, void* d_ws, size_t ws_size,
                              hipStream_t stream) {
  const float* x      = (const float*)d_in[0];
  const int*   src    = (const int*)d_in[1];
  const int*   dst    = (const int*)d_in[2];
  const float* w0_lin = (const float*)d_in[3];
  const float* b0_lin = (const float*)d_in[4];
  const float* w0_self= (const float*)d_in[5];
  const float* b0_self= (const float*)d_in[6];
  const float* bias0  = (const float*)d_in[7];
  const float* w_lin  = (const float*)d_in[8];
  const float* b_lin  = (const float*)d_in[9];
  const float* w_self = (const float*)d_in[10];
  const float* b_self = (const float*)d_in[11];
  const float* bias   = (const float*)d_in[12];
  const float* w_last = (const float*)d_in[13];
  const float* b_last = (const float*)d_in[14];
  float* out = (float*)d_out;

  char* w = (char*)d_ws;
  int* row_ptr  = (int*)w;  w += align16((size_t)(NNODES + 1) * 4);
  int* cursor   = (int*)w;  w += align16((size_t)NNODES * 4);   // doubles as cnt
  int* partials = (int*)w;  w += 512;
  int* srcs     = (int*)w;  w += align16((size_t)NEDGES * 4);
  float* z      = (float*)w; w += (size_t)NNODES * 64 * 4;
  float* s      = (float*)w; w += (size_t)NNODES * 64 * 4;
  float* h      = (float*)w; w += (size_t)NNODES * 64 * 4;

  int* cnt = cursor;  // reuse: cnt needed only until scan, cursor written after

  // ---- CSR build ----
  k_zero<<<(NNODES + 255) / 256, 256, 0, stream>>>(cnt, NNODES);
  k_hist<<<(NEDGES + 255) / 256, 256, 0, stream>>>(dst, cnt);
  k_scan1<<<NCHUNK, SCAN_B, 0, stream>>>(cnt, row_ptr, partials);
  k_scan2<<<1, 64, 0, stream>>>(partials, row_ptr);
  k_scan3<<<NCHUNK, SCAN_B, 0, stream>>>(row_ptr, partials);
  k_cursor<<<(NNODES + 255) / 256, 256, 0, stream>>>(row_ptr, cursor);
  k_place<<<(NEDGES + 255) / 256, 256, 0, stream>>>(src, dst, cursor, srcs);

  // ---- layer 0 (IN = 128, input x) ----
  k_transform<INF><<<NNODES / 16, 256, 0, stream>>>(x, w0_lin, w0_self, b0_lin, b0_self,
                                                    bias0, z, s);
  k_aggregate<<<NNODES / 4, 256, 0, stream>>>(row_ptr, srcs, z, s, w_last, b_last, h, out, 0);

  // ---- layers 1..5 (IN = 64) ----
  for (int l = 1; l < NLAYERS; ++l) {
    int i = l - 1;
    k_transform<UNITS><<<NNODES / 16, 256, 0, stream>>>(
        h, w_lin + (size_t)i * UNITS * UNITS, w_self + (size_t)i * UNITS * UNITS,
        b_lin + (size_t)i * UNITS, b_self + (size_t)i * UNITS, bias + (size_t)i * UNITS, z, s);
    k_aggregate<<<NNODES / 4, 256, 0, stream>>>(row_ptr, srcs, z, s,
                                                w_last + (size_t)l * UNITS * OUTF, b_last,
                                                h, out, l);
  }
}

// Round 2
// 786.860 us; speedup vs baseline: 1.1452x; 1.1452x over previous
//
#include <hip/hip_runtime.h>

#define NNODES 50000
#define NEDGES 1600000
#define INF 128
#define UNITS 64
#define OUTF 40
#define NLAYERS 6
#define SCAN_B 512
#define NCHUNK ((NNODES + SCAN_B - 1) / SCAN_B)  // 98

__device__ __forceinline__ ushort f2bf(float f) {
  unsigned u = __float_as_uint(f);
  unsigned r = (u + 0x7fffu + ((u >> 16) & 1u)) >> 16;
  return (ushort)r;
}
__device__ __forceinline__ float2 bf2_unpack(unsigned v) {
  float2 r;
  r.x = __uint_as_float(v << 16);
  r.y = __uint_as_float(v & 0xffff0000u);
  return r;
}

__global__ void k_zero(int* __restrict__ p, int n) {
  int i = blockIdx.x * 256 + threadIdx.x;
  if (i < n) p[i] = 0;
}

__global__ void k_hist(const int* __restrict__ dst, int* __restrict__ cnt) {
  int e = blockIdx.x * 256 + threadIdx.x;
  if (e < NEDGES) atomicAdd(&cnt[dst[e]], 1);
}

__global__ void k_scan1(const int* __restrict__ cnt, int* __restrict__ row_ptr,
                        int* __restrict__ partials) {
  __shared__ int sh[SCAN_B];
  int i = blockIdx.x * SCAN_B + threadIdx.x;
  int v = (i < NNODES) ? cnt[i] : 0;
  sh[threadIdx.x] = v;
  __syncthreads();
  for (int off = 1; off < SCAN_B; off <<= 1) {
    int t = (threadIdx.x >= off) ? sh[threadIdx.x - off] : 0;
    __syncthreads();
    sh[threadIdx.x] += t;
    __syncthreads();
  }
  if (i < NNODES) row_ptr[i + 1] = sh[threadIdx.x];
  if (threadIdx.x == SCAN_B - 1) partials[blockIdx.x] = sh[SCAN_B - 1];
}

__global__ void k_scan2(int* __restrict__ partials, int* __restrict__ row_ptr) {
  if (threadIdx.x == 0 && blockIdx.x == 0) {
    int run = 0;
    for (int i = 0; i < NCHUNK; ++i) { int t = partials[i]; partials[i] = run; run += t; }
    row_ptr[0] = 0;
  }
}

// finalize row_ptr AND derive cursor[i] = row_ptr[i] (cursor aliases cnt; read-then-write same slot)
__global__ void k_scan3(int* __restrict__ row_ptr, const int* __restrict__ partials,
                        int* __restrict__ cursor, const int* __restrict__ cnt) {
  int i = blockIdx.x * SCAN_B + threadIdx.x;
  if (i < NNODES) {
    int v = row_ptr[i + 1] + partials[blockIdx.x];
    int c = cnt[i];
    row_ptr[i + 1] = v;
    cursor[i] = v - c;
  }
}

__global__ void k_place(const int* __restrict__ src, const int* __restrict__ dst,
                        int* __restrict__ cursor, int* __restrict__ srcs) {
  int e = blockIdx.x * 256 + threadIdx.x;
  if (e < NEDGES) {
    int p = atomicAdd(&cursor[dst[e]], 1);
    srcs[p] = src[e];
  }
}

// z(bf16) = h @ wl ; s(f32) = h @ ws + (bl + bs + bias)
// block = 256 threads = 4 waves; each wave handles 4 consecutive nodes (16/block).
template <int IN>
__global__ void k_transform(const float* __restrict__ h, const float* __restrict__ wl,
                            const float* __restrict__ ws, const float* __restrict__ bl,
                            const float* __restrict__ bs, const float* __restrict__ bias,
                            ushort* __restrict__ z, float* __restrict__ s) {
  __shared__ float lds_h[16 * IN];
  const float* hbase = h + (size_t)blockIdx.x * 16 * IN;
  for (int idx = threadIdx.x; idx < 16 * IN; idx += 256) lds_h[idx] = hbase[idx];
  __syncthreads();
  int wave = threadIdx.x >> 6;
  int lane = threadIdx.x & 63;
  int nb = blockIdx.x * 16 + wave * 4;
  const float* hl = &lds_h[(wave * 4) * IN];
  float za0 = 0, za1 = 0, za2 = 0, za3 = 0;
  float sa0 = 0, sa1 = 0, sa2 = 0, sa3 = 0;
#pragma unroll 4
  for (int k = 0; k < IN; ++k) {
    float wlv = wl[k * 64 + lane];
    float wsv = ws[k * 64 + lane];
    float h0 = hl[k], h1 = hl[IN + k], h2 = hl[2 * IN + k], h3 = hl[3 * IN + k];
    za0 += h0 * wlv; sa0 += h0 * wsv;
    za1 += h1 * wlv; sa1 += h1 * wsv;
    za2 += h2 * wlv; sa2 += h2 * wsv;
    za3 += h3 * wlv; sa3 += h3 * wsv;
  }
  float c = bl[lane] + bs[lane] + bias[lane];
  z[(size_t)(nb + 0) * 64 + lane] = f2bf(za0); s[(size_t)(nb + 0) * 64 + lane] = sa0 + c;
  z[(size_t)(nb + 1) * 64 + lane] = f2bf(za1); s[(size_t)(nb + 1) * 64 + lane] = sa1 + c;
  z[(size_t)(nb + 2) * 64 + lane] = f2bf(za2); s[(size_t)(nb + 2) * 64 + lane] = sa2 + c;
  z[(size_t)(nb + 3) * 64 + lane] = f2bf(za3); s[(size_t)(nb + 3) * 64 + lane] = sa3 + c;
}

// agg = sum_{e in CSR(node)} z[src_e] (bf16); h = relu(agg + s); out (+)= h @ wlast_slice
// block = 256 = 4 waves, one node per wave. 32 lanes per edge (bf16x2/lane), 2 edges
// in parallel across wave halves, unroll 4 => 8 edges in flight.
__global__ void k_aggregate(const int* __restrict__ row_ptr, const int* __restrict__ srcs,
                            const ushort* __restrict__ z, const float* __restrict__ s,
                            const float* __restrict__ wlast, const float* __restrict__ blast,
                            float* __restrict__ h_out, float* __restrict__ out, int layer) {
  __shared__ float lds_h[4][64];
  int wave = threadIdx.x >> 6;
  int lane = threadIdx.x & 63;
  int half = lane >> 5;    // which edge of the pair
  int fl = lane & 31;      // feature-pair index
  int node = blockIdx.x * 4 + wave;
  int start = row_ptr[node];
  int end = row_ptr[node + 1];
  float2 a0 = {0.f, 0.f}, a1 = {0.f, 0.f}, a2 = {0.f, 0.f}, a3 = {0.f, 0.f};
  const unsigned* zw = (const unsigned*)z;
  int e = start + half;
  for (; e + 6 < end; e += 8) {
    int s0 = srcs[e], s1 = srcs[e + 2], s2 = srcs[e + 4], s3 = srcs[e + 6];
    float2 v0 = bf2_unpack(zw[(size_t)s0 * 32 + fl]);
    float2 v1 = bf2_unpack(zw[(size_t)s1 * 32 + fl]);
    float2 v2 = bf2_unpack(zw[(size_t)s2 * 32 + fl]);
    float2 v3 = bf2_unpack(zw[(size_t)s3 * 32 + fl]);
    a0.x += v0.x; a0.y += v0.y;
    a1.x += v1.x; a1.y += v1.y;
    a2.x += v2.x; a2.y += v2.y;
    a3.x += v3.x; a3.y += v3.y;
  }
  for (; e < end; e += 2) {
    float2 v = bf2_unpack(zw[(size_t)srcs[e] * 32 + fl]);
    a0.x += v.x; a0.y += v.y;
  }
  float2 acc;
  acc.x = (a0.x + a1.x) + (a2.x + a3.x);
  acc.y = (a0.y + a1.y) + (a2.y + a3.y);
  // combine the two halves (feature-pair fl lives at lanes fl and fl+32)
  acc.x += __shfl_xor(acc.x, 32);
  acc.y += __shfl_xor(acc.y, 32);
  if (half == 0) {
    float2 sv = ((const float2*)(s + (size_t)node * 64))[fl];
    float hx = fmaxf(acc.x + sv.x, 0.f);
    float hy = fmaxf(acc.y + sv.y, 0.f);
    float2 hv = {hx, hy};
    ((float2*)(h_out + (size_t)node * 64))[fl] = hv;
    lds_h[wave][2 * fl] = hx;
    lds_h[wave][2 * fl + 1] = hy;
  }
  __syncthreads();
  if (lane < OUTF) {
    float o = 0.f;
#pragma unroll 8
    for (int d = 0; d < 64; ++d) o += lds_h[wave][d] * wlast[d * OUTF + lane];
    float prev = (layer == 0) ? blast[lane] : out[(size_t)node * OUTF + lane];
    out[(size_t)node * OUTF + lane] = prev + o;
  }
}

static inline size_t align16(size_t x) { return (x + 15) & ~(size_t)15; }

extern "C" void kernel_launch(void* const* d_in, const int* in_sizes, int n_in,
                              void* d_out, int out_size, void* d_ws, size_t ws_size,
                              hipStream_t stream) {
  const float* x      = (const float*)d_in[0];
  const int*   src    = (const int*)d_in[1];
  const int*   dst    = (const int*)d_in[2];
  const float* w0_lin = (const float*)d_in[3];
  const float* b0_lin = (const float*)d_in[4];
  const float* w0_self= (const float*)d_in[5];
  const float* b0_self= (const float*)d_in[6];
  const float* bias0  = (const float*)d_in[7];
  const float* w_lin  = (const float*)d_in[8];
  const float* b_lin  = (const float*)d_in[9];
  const float* w_self = (const float*)d_in[10];
  const float* b_self = (const float*)d_in[11];
  const float* bias   = (const float*)d_in[12];
  const float* w_last = (const float*)d_in[13];
  const float* b_last = (const float*)d_in[14];
  float* out = (float*)d_out;

  char* w = (char*)d_ws;
  int* row_ptr  = (int*)w;  w += align16((size_t)(NNODES + 1) * 4);
  int* cursor   = (int*)w;  w += align16((size_t)NNODES * 4);   // doubles as cnt
  int* partials = (int*)w;  w += 512;
  int* srcs     = (int*)w;  w += align16((size_t)NEDGES * 4);
  ushort* z     = (ushort*)w; w += align16((size_t)NNODES * 64 * 2);
  float* s      = (float*)w;  w += (size_t)NNODES * 64 * 4;
  float* h      = (float*)w;  w += (size_t)NNODES * 64 * 4;

  int* cnt = cursor;  // aliased: cnt live until scan3, which converts it to cursor in place

  // ---- CSR build ----
  k_zero<<<(NNODES + 255) / 256, 256, 0, stream>>>(cnt, NNODES);
  k_hist<<<(NEDGES + 255) / 256, 256, 0, stream>>>(dst, cnt);
  k_scan1<<<NCHUNK, SCAN_B, 0, stream>>>(cnt, row_ptr, partials);
  k_scan2<<<1, 64, 0, stream>>>(partials, row_ptr);
  k_scan3<<<NCHUNK, SCAN_B, 0, stream>>>(row_ptr, partials, cursor, cnt);
  k_place<<<(NEDGES + 255) / 256, 256, 0, stream>>>(src, dst, cursor, srcs);

  // ---- layer 0 (IN = 128, input x) ----
  k_transform<INF><<<NNODES / 16, 256, 0, stream>>>(x, w0_lin, w0_self, b0_lin, b0_self,
                                                    bias0, z, s);
  k_aggregate<<<NNODES / 4, 256, 0, stream>>>(row_ptr, srcs, z, s, w_last, b_last, h, out, 0);

  // ---- layers 1..5 (IN = 64) ----
  for (int l = 1; l < NLAYERS; ++l) {
    int i = l - 1;
    k_transform<UNITS><<<NNODES / 16, 256, 0, stream>>>(
        h, w_lin + (size_t)i * UNITS * UNITS, w_self + (size_t)i * UNITS * UNITS,
        b_lin + (size_t)i * UNITS, b_self + (size_t)i * UNITS, bias + (size_t)i * UNITS, z, s);
    k_aggregate<<<NNODES / 4, 256, 0, stream>>>(row_ptr, srcs, z, s,
                                                w_last + (size_t)l * UNITS * OUTF, b_last,
                                                h, out, l);
  }
}

// Round 3
// 530.485 us; speedup vs baseline: 1.6986x; 1.4833x over previous
//
#include <hip/hip_runtime.h>

#define NNODES 50000
#define NEDGES 1600000
#define INF 128
#define UNITS 64
#define OUTF 40
#define NLAYERS 6
#define NBUCK 196          // ceil(50000/256), bucket = dst >> 8
#define BCAP 9472          // per-bucket capacity (mean 8192, sigma ~90 -> 14 sigma)
#define CHUNK 8192         // edges per k_bin block
#define NBINB ((NEDGES + CHUNK - 1) / CHUNK)  // 196

__device__ __forceinline__ ushort f2bf(float f) {
  unsigned u = __float_as_uint(f);
  unsigned r = (u + 0x7fffu + ((u >> 16) & 1u)) >> 16;
  return (ushort)r;
}
__device__ __forceinline__ float2 bf2_unpack(unsigned v) {
  float2 r;
  r.x = __uint_as_float(v << 16);
  r.y = __uint_as_float(v & 0xffff0000u);
  return r;
}

// Pass 1: bin edges by dst>>8. packed = (bucket<<24)|(src<<8)|(dst&255)
__global__ void k_bin(const int* __restrict__ src, const int* __restrict__ dst,
                      int* __restrict__ bucket_cursor, unsigned* __restrict__ binned) {
  __shared__ unsigned sh_pack[CHUNK];
  __shared__ int sh_cnt[NBUCK];
  __shared__ int sh_base[NBUCK];
  int tid = threadIdx.x;
  int e0 = blockIdx.x * CHUNK;
  int n = min(CHUNK, NEDGES - e0);
  for (int j = tid; j < NBUCK; j += 256) sh_cnt[j] = 0;
  __syncthreads();
  for (int j = tid; j < n; j += 256) {
    int s = src[e0 + j];
    int d = dst[e0 + j];
    sh_pack[j] = ((unsigned)(d >> 8) << 24) | ((unsigned)s << 8) | (unsigned)(d & 255);
    atomicAdd(&sh_cnt[d >> 8], 1);
  }
  __syncthreads();
  if (tid < NBUCK) {
    sh_base[tid] = atomicAdd(&bucket_cursor[tid], sh_cnt[tid]);
    sh_cnt[tid] = 0;  // reuse as local rank cursor
  }
  __syncthreads();
  for (int j = tid; j < n; j += 256) {
    unsigned p = sh_pack[j];
    int b = p >> 24;
    int r = atomicAdd(&sh_cnt[b], 1);
    int idx = sh_base[b] + r;
    if (idx < BCAP) binned[(size_t)b * BCAP + idx] = p;
  }
}

// Exclusive scan over bucket sizes -> bucket_base
__global__ void k_bucket_scan(const int* __restrict__ bucket_cursor,
                              int* __restrict__ bucket_base) {
  __shared__ int sh[256];
  int tid = threadIdx.x;
  int c = (tid < NBUCK) ? min(bucket_cursor[tid], BCAP) : 0;
  sh[tid] = c;
  __syncthreads();
  for (int off = 1; off < 256; off <<= 1) {
    int t = (tid >= off) ? sh[tid - off] : 0;
    __syncthreads();
    sh[tid] += t;
    __syncthreads();
  }
  if (tid < NBUCK) bucket_base[tid] = sh[tid] - c;
}

// Pass 2: per bucket — LDS hist + scan over 256 local nodes -> row_ptr,
// then place srcs (ushort) within the bucket's L2-resident segment.
__global__ void k_build(const int* __restrict__ bucket_cursor, const int* __restrict__ bucket_base,
                        const unsigned* __restrict__ binned, int* __restrict__ row_ptr,
                        ushort* __restrict__ srcs) {
  __shared__ unsigned sh_packed[BCAP];
  __shared__ int sh_cnt[256];
  __shared__ int sh_off[256];
  int tid = threadIdx.x;
  int b = blockIdx.x;
  int cnt = min(bucket_cursor[b], BCAP);
  int base = bucket_base[b];
  for (int i = tid; i < cnt; i += 256) sh_packed[i] = binned[(size_t)b * BCAP + i];
  sh_cnt[tid] = 0;
  __syncthreads();
  for (int i = tid; i < cnt; i += 256) atomicAdd(&sh_cnt[sh_packed[i] & 255], 1);
  __syncthreads();
  int c = sh_cnt[tid];
  sh_off[tid] = c;
  __syncthreads();
  for (int off = 1; off < 256; off <<= 1) {
    int t = (tid >= off) ? sh_off[tid - off] : 0;
    __syncthreads();
    sh_off[tid] += t;
    __syncthreads();
  }
  int excl = sh_off[tid] - c;
  int node = b * 256 + tid;
  if (node <= NNODES) row_ptr[node] = base + excl;
  sh_off[tid] = excl;  // becomes the placement cursor
  __syncthreads();
  for (int i = tid; i < cnt; i += 256) {
    unsigned p = sh_packed[i];
    int dl = p & 255;
    int pos = atomicAdd(&sh_off[dl], 1);
    srcs[base + pos] = (ushort)((p >> 8) & 0xffff);
  }
}

// z(bf16) = h @ wl ; s(f32) = h @ ws + (bl + bs + bias)
template <int IN>
__global__ void k_transform(const float* __restrict__ h, const float* __restrict__ wl,
                            const float* __restrict__ ws, const float* __restrict__ bl,
                            const float* __restrict__ bs, const float* __restrict__ bias,
                            ushort* __restrict__ z, float* __restrict__ s) {
  __shared__ float lds_h[16 * IN];
  const float* hbase = h + (size_t)blockIdx.x * 16 * IN;
  for (int idx = threadIdx.x; idx < 16 * IN; idx += 256) lds_h[idx] = hbase[idx];
  __syncthreads();
  int wave = threadIdx.x >> 6;
  int lane = threadIdx.x & 63;
  int nb = blockIdx.x * 16 + wave * 4;
  const float* hl = &lds_h[(wave * 4) * IN];
  float za0 = 0, za1 = 0, za2 = 0, za3 = 0;
  float sa0 = 0, sa1 = 0, sa2 = 0, sa3 = 0;
#pragma unroll 4
  for (int k = 0; k < IN; ++k) {
    float wlv = wl[k * 64 + lane];
    float wsv = ws[k * 64 + lane];
    float h0 = hl[k], h1 = hl[IN + k], h2 = hl[2 * IN + k], h3 = hl[3 * IN + k];
    za0 += h0 * wlv; sa0 += h0 * wsv;
    za1 += h1 * wlv; sa1 += h1 * wsv;
    za2 += h2 * wlv; sa2 += h2 * wsv;
    za3 += h3 * wlv; sa3 += h3 * wsv;
  }
  float c = bl[lane] + bs[lane] + bias[lane];
  z[(size_t)(nb + 0) * 64 + lane] = f2bf(za0); s[(size_t)(nb + 0) * 64 + lane] = sa0 + c;
  z[(size_t)(nb + 1) * 64 + lane] = f2bf(za1); s[(size_t)(nb + 1) * 64 + lane] = sa1 + c;
  z[(size_t)(nb + 2) * 64 + lane] = f2bf(za2); s[(size_t)(nb + 2) * 64 + lane] = sa2 + c;
  z[(size_t)(nb + 3) * 64 + lane] = f2bf(za3); s[(size_t)(nb + 3) * 64 + lane] = sa3 + c;
}

// agg over CSR with 8 lanes/edge, dwordx4 per lane, 16 edges in flight per wave.
__global__ void k_aggregate(const int* __restrict__ row_ptr, const ushort* __restrict__ srcs,
                            const ushort* __restrict__ z, const float* __restrict__ s,
                            const float* __restrict__ wlast, const float* __restrict__ blast,
                            float* __restrict__ h_out, float* __restrict__ out, int layer) {
  __shared__ float lds_h[4][64];
  int wave = threadIdx.x >> 6;
  int lane = threadIdx.x & 63;
  int g = lane >> 3;   // edge slot within wave
  int fi = lane & 7;   // 16B chunk of the 128B row
  int node = blockIdx.x * 4 + wave;
  int start = row_ptr[node];
  int end = row_ptr[node + 1];
  float a0 = 0, a1 = 0, a2 = 0, a3 = 0, a4 = 0, a5 = 0, a6 = 0, a7 = 0;
  const uint4* zv = (const uint4*)z;
  int e = start + g;
  for (; e + 8 < end; e += 16) {
    int s0 = srcs[e];
    int s1 = srcs[e + 8];
    uint4 v0 = zv[(size_t)s0 * 8 + fi];
    uint4 v1 = zv[(size_t)s1 * 8 + fi];
    float2 p0 = bf2_unpack(v0.x), p1 = bf2_unpack(v0.y), p2 = bf2_unpack(v0.z), p3 = bf2_unpack(v0.w);
    float2 q0 = bf2_unpack(v1.x), q1 = bf2_unpack(v1.y), q2 = bf2_unpack(v1.z), q3 = bf2_unpack(v1.w);
    a0 += p0.x + q0.x; a1 += p0.y + q0.y;
    a2 += p1.x + q1.x; a3 += p1.y + q1.y;
    a4 += p2.x + q2.x; a5 += p2.y + q2.y;
    a6 += p3.x + q3.x; a7 += p3.y + q3.y;
  }
  if (e < end) {
    uint4 v = zv[(size_t)srcs[e] * 8 + fi];
    float2 p0 = bf2_unpack(v.x), p1 = bf2_unpack(v.y), p2 = bf2_unpack(v.z), p3 = bf2_unpack(v.w);
    a0 += p0.x; a1 += p0.y; a2 += p1.x; a3 += p1.y;
    a4 += p2.x; a5 += p2.y; a6 += p3.x; a7 += p3.y;
  }
#pragma unroll
  for (int m = 8; m < 64; m <<= 1) {
    a0 += __shfl_xor(a0, m); a1 += __shfl_xor(a1, m);
    a2 += __shfl_xor(a2, m); a3 += __shfl_xor(a3, m);
    a4 += __shfl_xor(a4, m); a5 += __shfl_xor(a5, m);
    a6 += __shfl_xor(a6, m); a7 += __shfl_xor(a7, m);
  }
  if (g == 0) {
    const float4* sp = (const float4*)(s + (size_t)node * 64 + fi * 8);
    float4 s0 = sp[0], s1 = sp[1];
    float h0 = fmaxf(a0 + s0.x, 0.f), h1 = fmaxf(a1 + s0.y, 0.f);
    float h2 = fmaxf(a2 + s0.z, 0.f), h3 = fmaxf(a3 + s0.w, 0.f);
    float h4 = fmaxf(a4 + s1.x, 0.f), h5 = fmaxf(a5 + s1.y, 0.f);
    float h6 = fmaxf(a6 + s1.z, 0.f), h7 = fmaxf(a7 + s1.w, 0.f);
    float4* hp = (float4*)(h_out + (size_t)node * 64 + fi * 8);
    hp[0] = make_float4(h0, h1, h2, h3);
    hp[1] = make_float4(h4, h5, h6, h7);
    float* lh = &lds_h[wave][fi * 8];
    lh[0] = h0; lh[1] = h1; lh[2] = h2; lh[3] = h3;
    lh[4] = h4; lh[5] = h5; lh[6] = h6; lh[7] = h7;
  }
  __syncthreads();
  if (lane < OUTF) {
    float o = 0.f;
#pragma unroll 8
    for (int d = 0; d < 64; ++d) o += lds_h[wave][d] * wlast[d * OUTF + lane];
    float prev = (layer == 0) ? blast[lane] : out[(size_t)node * OUTF + lane];
    out[(size_t)node * OUTF + lane] = prev + o;
  }
}

static inline size_t align16(size_t x) { return (x + 15) & ~(size_t)15; }

extern "C" void kernel_launch(void* const* d_in, const int* in_sizes, int n_in,
                              void* d_out, int out_size, void* d_ws, size_t ws_size,
                              hipStream_t stream) {
  const float* x      = (const float*)d_in[0];
  const int*   src    = (const int*)d_in[1];
  const int*   dst    = (const int*)d_in[2];
  const float* w0_lin = (const float*)d_in[3];
  const float* b0_lin = (const float*)d_in[4];
  const float* w0_self= (const float*)d_in[5];
  const float* b0_self= (const float*)d_in[6];
  const float* bias0  = (const float*)d_in[7];
  const float* w_lin  = (const float*)d_in[8];
  const float* b_lin  = (const float*)d_in[9];
  const float* w_self = (const float*)d_in[10];
  const float* b_self = (const float*)d_in[11];
  const float* bias   = (const float*)d_in[12];
  const float* w_last = (const float*)d_in[13];
  const float* b_last = (const float*)d_in[14];
  float* out = (float*)d_out;

  char* w = (char*)d_ws;
  int* row_ptr       = (int*)w;  w += align16((size_t)(NNODES + 1) * 4);
  int* bucket_cursor = (int*)w;  w += align16((size_t)NBUCK * 4);
  int* bucket_base   = (int*)w;  w += align16(256 * 4);
  ushort* srcs       = (ushort*)w; w += align16((size_t)NEDGES * 2);
  // union region: binned (7.43 MB) aliases z (6.4 MB) + head of s; binned is dead
  // before the first k_transform writes z/s (same-stream sequencing).
  char* union_base = w;
  ushort* z = (ushort*)union_base;
  float* s  = (float*)(union_base + align16((size_t)NNODES * 64 * 2));
  float* h  = (float*)(union_base + align16((size_t)NNODES * 64 * 2) + (size_t)NNODES * 64 * 4);
  unsigned* binned = (unsigned*)union_base;

  // ---- CSR build (bucketed) ----
  hipMemsetAsync(bucket_cursor, 0, NBUCK * 4, stream);
  k_bin<<<NBINB, 256, 0, stream>>>(src, dst, bucket_cursor, binned);
  k_bucket_scan<<<1, 256, 0, stream>>>(bucket_cursor, bucket_base);
  k_build<<<NBUCK, 256, 0, stream>>>(bucket_cursor, bucket_base, binned, row_ptr, srcs);

  // ---- layer 0 (IN = 128, input x) ----
  k_transform<INF><<<NNODES / 16, 256, 0, stream>>>(x, w0_lin, w0_self, b0_lin, b0_self,
                                                    bias0, z, s);
  k_aggregate<<<NNODES / 4, 256, 0, stream>>>(row_ptr, srcs, z, s, w_last, b_last, h, out, 0);

  // ---- layers 1..5 (IN = 64) ----
  for (int l = 1; l < NLAYERS; ++l) {
    int i = l - 1;
    k_transform<UNITS><<<NNODES / 16, 256, 0, stream>>>(
        h, w_lin + (size_t)i * UNITS * UNITS, w_self + (size_t)i * UNITS * UNITS,
        b_lin + (size_t)i * UNITS, b_self + (size_t)i * UNITS, bias + (size_t)i * UNITS, z, s);
    k_aggregate<<<NNODES / 4, 256, 0, stream>>>(row_ptr, srcs, z, s,
                                                w_last + (size_t)l * UNITS * OUTF, b_last,
                                                h, out, l);
  }
}